// Round 19
// baseline (148.333 us; speedup 1.0000x reference)
//
#include <hip/hip_runtime.h>
#include <hip/hip_bf16.h>

typedef __bf16 bf16x8 __attribute__((ext_vector_type(8)));
typedef float f32x4 __attribute__((ext_vector_type(4)));

// row-pair XOR swizzle: logical (row n of 64B, 16B-chunk k) -> byte offset
__device__ __forceinline__ int swz(int n, int k) {
  int pair = n >> 1;
  int s = (((n & 1) << 2) | k) ^ (pair & 7);
  return (pair << 7) + (s << 4);
}

__device__ __forceinline__ void load_lds16(const void* g, void* l) {
  __builtin_amdgcn_global_load_lds((const __attribute__((address_space(1))) void*)g,
                                   (__attribute__((address_space(3))) void*)l, 16, 0, 0);
}

// ---------- merged prep (256 thr): blocks 0..6143 = prep_x half-rows, 6144..7167 = prep_w ----------
__global__ __launch_bounds__(256) void prep_kernel(
    const float* __restrict__ x, const float* __restrict__ z,
    const float* __restrict__ gw, const float* __restrict__ pww,
    const float* __restrict__ dww, const float* __restrict__ base,
    __hip_bfloat16* __restrict__ xn, __hip_bfloat16* __restrict__ Wt) {
  __shared__ float tile[64][97];   // 24832 B; prep_w aliases the front
  int gid = blockIdx.x;
  int tid = threadIdx.x;

  if (gid < 6144) {
    // ---------------- prep_x (half: 64 ic) ----------------
    int b = gid / 192, rem = gid - b * 192;
    int h = rem >> 1, half = rem & 1;
    const float* src = x + ((size_t)(b * 128 + half * 64)) * 9216 + h * 96;
    for (int f = tid; f < 1536; f += 256) {   // 64 ic x 24 float4
      int ic = f / 24, w4 = f - ic * 24;
      float4 v = *(const float4*)(src + (size_t)ic * 9216 + w4 * 4);
      tile[ic][w4 * 4 + 0] = v.x; tile[ic][w4 * 4 + 1] = v.y;
      tile[ic][w4 * 4 + 2] = v.z; tile[ic][w4 * 4 + 3] = v.w;
    }
    __syncthreads();
    __hip_bfloat16* bb  = xn + (size_t)b * 4 * 307328 + (size_t)half * 2 * 307328;
    __hip_bfloat16* dst = bb + (h + 1) * 3136 + 32;
    for (int o = tid; o < 768; o += 256) {   // 16B units, 2 grps
      int grp = o / 384, rem2 = o - grp * 384;
      int w = rem2 >> 2, chunk = rem2 & 3;
      __hip_bfloat16 tmp[8];
      #pragma unroll
      for (int e = 0; e < 8; e++) tmp[e] = __float2bfloat16(tile[grp * 32 + chunk * 8 + e][w]);
      *(uint4*)(dst + (size_t)grp * 307328 + w * 32 + chunk * 8) = *(uint4*)tmp;
    }
    // left/right halo cells of this row (ph = h+1), 2 grps
    if (tid < 16) {
      int grp = tid >> 3, r = tid & 7;
      int pw = (r >> 2) ? 97 : 0, k = r & 3;
      *(uint4*)(bb + (size_t)grp * 307328 + ((h + 1) * 98 + pw) * 32 + k * 8) = make_uint4(0, 0, 0, 0);
    }
    // top/bottom halo rows, 2 grps
    if (h == 0 || h == 95) {
      int ph = (h == 0) ? 0 : 97;
      for (int u = tid; u < 784; u += 256) {
        int grp = u / 392, rem3 = u - grp * 392;
        int pw = rem3 >> 2, k = rem3 & 3;
        *(uint4*)(bb + (size_t)grp * 307328 + (ph * 98 + pw) * 32 + k * 8) = make_uint4(0, 0, 0, 0);
      }
    }
  } else {
    // ---------------- prep_w ----------------
    float* zs  = &tile[0][0];          // 256 floats
    float (*res)[5] = (float (*)[5])(&tile[0][0] + 256);   // [138][5]
    int pw_id = gid - 6144;
    int oc = pw_id & 127;
    int b0 = (pw_id >> 7) * 4;
    zs[tid] = z[b0 * 64 + tid];
    __syncthreads();
    int row = tid;
    if (row < 138) {
      const float* wrow = (row == 0) ? gw + (size_t)oc * 64
                        : (row < 10) ? dww + ((size_t)oc * 9 + (row - 1)) * 64
                                     : pww + ((size_t)oc * 128 + (row - 10)) * 64;
      float wr[64];
      #pragma unroll
      for (int i = 0; i < 16; i++) {
        float4 v = ((const float4*)wrow)[i];
        wr[4*i] = v.x; wr[4*i+1] = v.y; wr[4*i+2] = v.z; wr[4*i+3] = v.w;
      }
      #pragma unroll
      for (int bb = 0; bb < 4; bb++) {
        float a = 0.f;
        #pragma unroll
        for (int i = 0; i < 64; i++) a += zs[bb * 64 + i] * wr[i];
        res[row][bb] = a;
      }
    }
    __syncthreads();
    for (int e = tid; e < 2304; e += 256) {   // bf162 units
      int icp = e & 15;
      int r1 = e >> 4;                  // 0..143
      int tap = r1 % 9, gb = r1 / 9;    // gb = bb*4+grp
      int grp = gb & 3, bb = gb >> 2;
      int b = b0 + bb;
      int ic = grp * 32 + icp * 2;
      int dy = tap / 3, dx = tap - dy * 3;
      float g = res[0][bb], d = res[1 + tap][bb];
      float p0 = res[10 + ic][bb], p1 = res[11 + ic][bb];
      const float* bp = base + ((size_t)(oc * 128 + ic)) * 9 + tap;
      __hip_bfloat162 o2 = {__float2bfloat16(bp[0] * g + p0 * d),
                            __float2bfloat16(bp[9] * g + p1 * d)};
      // dx-major slot (dx*3+dy) for conv's dx-outer phases
      *(__hip_bfloat162*)(Wt + ((((size_t)(b * 4 + grp)) * 9 + dx * 3 + dy) * 128 + oc) * 32 + icp * 2) = o2;
    }
  }
}

// ---------- conv: 256px x 128oc per block, waves = 64px x 128oc, 12 dx-outer phases ----------
// B-reads amortized over full oc per wave: 32 ds_read / 96 MFMA per wave-phase
// (total LDS demand -20%). x staged once per px-tile. One barrier per steady phase.
__global__ __launch_bounds__(256, 2) void conv_kernel(
    const __hip_bfloat16* __restrict__ xn, const __hip_bfloat16* __restrict__ Wt,
    float* __restrict__ out) {
  __shared__ __align__(16) char smem[73728];
  char* const xt  = smem;               // 24576 B (1536 slots; 1360 used)
  char* const wb0 = smem + 24576;       // 24576 B each (3 dy-slots x 128 oc x 64 B)
  char* const wb1 = smem + 49152;

  int bid = blockIdx.x;
  int X = bid & 7, q = bid >> 3;        // XCD pin: 144 blocks (4 samples) per XCD
  int logical = X * 144 + q;
  int b   = logical / 36;
  int rem = logical - b * 36;
  int hr  = rem / 3;
  int wc  = rem - hr * 3;
  int h0 = hr * 8, w0 = wc * 32;

  int tid = threadIdx.x;
  int lane = tid & 63, wid = tid >> 6;
  int l15 = lane & 15, lk = lane >> 4;

  // x-stage source offsets (6/thread, clamp keeps per-wave issue count uniform)
  int xoff[6];
  #pragma unroll
  for (int j = 0; j < 6; j++) {
    int p = j * 256 + tid; if (p > 1359) p = 1359;
    int pair = p >> 3, v = (p & 7) ^ (pair & 7);
    int n = (pair << 1) | (v >> 2), k = v & 3;
    int hh = n / 34, ww = n - hh * 34;
    xoff[j] = ((h0 + hh) * 98 + (w0 + ww)) * 32 + k * 8;
  }
  // w-stage source offsets (6/thread, full 128 oc x 3 dy per phase = 24 KB)
  int wsoff[6];
  #pragma unroll
  for (int i = 0; i < 6; i++) {
    int p = i * 256 + tid;
    int pair = p >> 3, v = (p & 7) ^ (pair & 7);
    int n = (pair << 1) | (v >> 2), k = v & 3;
    wsoff[i] = n * 32 + k * 8;          // n = dy*128 + oc
  }

  const __hip_bfloat16* xbase = xn + (size_t)b * 4 * 307328;
  const __hip_bfloat16* wbase = Wt + (size_t)b * 147456;

  f32x4 acc[4][8];
  #pragma unroll
  for (int i = 0; i < 4; i++)
    #pragma unroll
    for (int j = 0; j < 8; j++) acc[i][j] = (f32x4){0.f, 0.f, 0.f, 0.f};

  // prologue: w(phase0) -> wb0 (6 loads), then x(grp0) -> xt (6 loads)
  #pragma unroll
  for (int i = 0; i < 6; i++)
    load_lds16(wbase + wsoff[i], wb0 + ((i * 256 + wid * 64) << 4));
  #pragma unroll
  for (int j = 0; j < 6; j++)
    load_lds16(xbase + xoff[j], xt + ((j * 256 + wid * 64) << 4));

#define PHASE(S, G, DX, WCUR, WNXT, DOX, DOW, PRE)                                 \
  {                                                                                \
    if (DOX) {                                                                     \
      const __hip_bfloat16* xsrc = xbase + (size_t)(G) * 307328;                   \
      _Pragma("unroll")                                                            \
      for (int j = 0; j < 6; j++)                                                  \
        load_lds16(xsrc + xoff[j], xt + ((j * 256 + wid * 64) << 4));              \
    }                                                                              \
    if (DOW) {                                                                     \
      const __hip_bfloat16* wsrc = wbase + (size_t)((G) * 9 + (DX) * 3 + 3) * 4096;\
      _Pragma("unroll")                                                            \
      for (int i = 0; i < 6; i++)                                                  \
        load_lds16(wsrc + wsoff[i], (WNXT) + ((i * 256 + wid * 64) << 4));         \
    }                                                                              \
    if (PRE) {                                                                     \
      asm volatile("s_waitcnt vmcnt(6)" ::: "memory");                             \
      __builtin_amdgcn_s_barrier();                                                \
    }                                                                              \
    bf16x8 afr[4][2];                                                              \
    _Pragma("unroll")                                                              \
    for (int rr = 0; rr < 4; rr++)                                                 \
      _Pragma("unroll")                                                            \
      for (int cc = 0; cc < 2; cc++)                                               \
        afr[rr][cc] = *(const bf16x8*)(xt +                                        \
            swz((wid * 2 + rr) * 34 + cc * 16 + l15 + (DX), lk));                  \
    _Pragma("unroll")                                                              \
    for (int dy = 0; dy < 3; dy++) {                                               \
      _Pragma("unroll")                                                            \
      for (int jh = 0; jh < 2; jh++) {                                             \
        bf16x8 bfr[4];                                                             \
        _Pragma("unroll")                                                          \
        for (int j4 = 0; j4 < 4; j4++)                                             \
          bfr[j4] = *(const bf16x8*)((WCUR) +                                      \
              swz(dy * 128 + jh * 64 + j4 * 16 + l15, lk));                        \
        _Pragma("unroll")                                                          \
        for (int i = 0; i < 4; i++)                                                \
          _Pragma("unroll")                                                        \
          for (int j4 = 0; j4 < 4; j4++)                                           \
            acc[i][jh * 4 + j4] = __builtin_amdgcn_mfma_f32_16x16x32_bf16(         \
                afr[(i >> 1) + dy][i & 1], bfr[j4], acc[i][jh * 4 + j4], 0, 0, 0); \
      }                                                                            \
    }                                                                              \
    if ((S) < 11) {                                                                \
      asm volatile("s_waitcnt vmcnt(0)" ::: "memory");                             \
      __builtin_amdgcn_s_barrier();                                                \
    }                                                                              \
  }

  PHASE(0,  0, 0, wb0, wb1, 0, 1, 1)
  PHASE(1,  0, 1, wb1, wb0, 0, 1, 0)
  PHASE(2,  0, 2, wb0, wb1, 0, 1, 0)
  PHASE(3,  1, 0, wb1, wb0, 1, 1, 1)
  PHASE(4,  1, 1, wb0, wb1, 0, 1, 0)
  PHASE(5,  1, 2, wb1, wb0, 0, 1, 0)
  PHASE(6,  2, 0, wb0, wb1, 1, 1, 1)
  PHASE(7,  2, 1, wb1, wb0, 0, 1, 0)
  PHASE(8,  2, 2, wb0, wb1, 0, 1, 0)
  PHASE(9,  3, 0, wb1, wb0, 1, 1, 1)
  PHASE(10, 3, 1, wb0, wb1, 0, 1, 0)
  PHASE(11, 3, 2, wb1, wb0, 0, 0, 0)
#undef PHASE

  // epilogue: j-outer so each 128B output line completes in consecutive stores
  float* ob = out + (size_t)b * 128 * 9216;
  #pragma unroll
  for (int j = 0; j < 8; j++) {
    int oc = j * 16 + l15;
    float* op = ob + (size_t)oc * 9216 + h0 * 96 + w0 + lk * 4;
    #pragma unroll
    for (int i = 0; i < 4; i++) {
      int m0 = wid * 64 + i * 16;
      *(f32x4*)(op + (m0 >> 5) * 96 + (m0 & 31)) = acc[i][j];
    }
  }
}

extern "C" void kernel_launch(void* const* d_in, const int* in_sizes, int n_in,
                              void* d_out, int out_size, void* d_ws, size_t ws_size,
                              hipStream_t stream) {
  const float* x   = (const float*)d_in[0];
  const float* z   = (const float*)d_in[1];
  const float* bw  = (const float*)d_in[2];
  const float* gw  = (const float*)d_in[3];
  const float* pww = (const float*)d_in[4];
  const float* dww = (const float*)d_in[5];
  float* out = (float*)d_out;

  char* ws = (char*)d_ws;
  __hip_bfloat16* xn = (__hip_bfloat16*)ws;                       // 78,675,968 B (padded)
  __hip_bfloat16* Wt = (__hip_bfloat16*)(ws + 78675968);          //  9,437,184 B

  hipLaunchKernelGGL(prep_kernel, dim3(7168), dim3(256), 0, stream,
                     x, z, gw, pww, dww, bw, xn, Wt);
  hipLaunchKernelGGL(conv_kernel, dim3(1152), dim3(256), 0, stream, xn, Wt, out);
}

// Round 20
// 135.008 us; speedup vs baseline: 1.0987x; 1.0987x over previous
//
#include <hip/hip_runtime.h>
#include <hip/hip_bf16.h>

typedef __bf16 bf16x8 __attribute__((ext_vector_type(8)));
typedef float f32x4 __attribute__((ext_vector_type(4)));

// row-pair XOR swizzle: logical (row n of 64B, 16B-chunk k) -> byte offset
__device__ __forceinline__ int swz(int n, int k) {
  int pair = n >> 1;
  int s = (((n & 1) << 2) | k) ^ (pair & 7);
  return (pair << 7) + (s << 4);
}

__device__ __forceinline__ void load_lds16(const void* g, void* l) {
  __builtin_amdgcn_global_load_lds((const __attribute__((address_space(1))) void*)g,
                                   (__attribute__((address_space(3))) void*)l, 16, 0, 0);
}

// ---------- merged prep (256 thr): blocks 0..6143 = prep_x half-rows, 6144..7167 = prep_w ----------
// prep_x: f32 NCHW -> bf16 padded [b][grp4][98][98][32ic], border-zero fused; 64 ic per block
// prep_w: z projections + merge -> Wt[b][grp4][slot9=dx*3+dy][oc128][32ic]
__global__ __launch_bounds__(256) void prep_kernel(
    const float* __restrict__ x, const float* __restrict__ z,
    const float* __restrict__ gw, const float* __restrict__ pww,
    const float* __restrict__ dww, const float* __restrict__ base,
    __hip_bfloat16* __restrict__ xn, __hip_bfloat16* __restrict__ Wt) {
  __shared__ float tile[64][97];   // 24832 B; prep_w aliases the front
  int gid = blockIdx.x;
  int tid = threadIdx.x;

  if (gid < 6144) {
    // ---------------- prep_x (half: 64 ic) ----------------
    int b = gid / 192, rem = gid - b * 192;
    int h = rem >> 1, half = rem & 1;
    const float* src = x + ((size_t)(b * 128 + half * 64)) * 9216 + h * 96;
    for (int f = tid; f < 1536; f += 256) {   // 64 ic x 24 float4
      int ic = f / 24, w4 = f - ic * 24;
      float4 v = *(const float4*)(src + (size_t)ic * 9216 + w4 * 4);
      tile[ic][w4 * 4 + 0] = v.x; tile[ic][w4 * 4 + 1] = v.y;
      tile[ic][w4 * 4 + 2] = v.z; tile[ic][w4 * 4 + 3] = v.w;
    }
    __syncthreads();
    __hip_bfloat16* bb  = xn + (size_t)b * 4 * 307328 + (size_t)half * 2 * 307328;
    __hip_bfloat16* dst = bb + (h + 1) * 3136 + 32;
    for (int o = tid; o < 768; o += 256) {   // 16B units, 2 grps
      int grp = o / 384, rem2 = o - grp * 384;
      int w = rem2 >> 2, chunk = rem2 & 3;
      __hip_bfloat16 tmp[8];
      #pragma unroll
      for (int e = 0; e < 8; e++) tmp[e] = __float2bfloat16(tile[grp * 32 + chunk * 8 + e][w]);
      *(uint4*)(dst + (size_t)grp * 307328 + w * 32 + chunk * 8) = *(uint4*)tmp;
    }
    // left/right halo cells of this row (ph = h+1), 2 grps
    if (tid < 16) {
      int grp = tid >> 3, r = tid & 7;
      int pw = (r >> 2) ? 97 : 0, k = r & 3;
      *(uint4*)(bb + (size_t)grp * 307328 + ((h + 1) * 98 + pw) * 32 + k * 8) = make_uint4(0, 0, 0, 0);
    }
    // top/bottom halo rows, 2 grps
    if (h == 0 || h == 95) {
      int ph = (h == 0) ? 0 : 97;
      for (int u = tid; u < 784; u += 256) {
        int grp = u / 392, rem3 = u - grp * 392;
        int pw = rem3 >> 2, k = rem3 & 3;
        *(uint4*)(bb + (size_t)grp * 307328 + (ph * 98 + pw) * 32 + k * 8) = make_uint4(0, 0, 0, 0);
      }
    }
  } else {
    // ---------------- prep_w ----------------
    float* zs  = &tile[0][0];          // 256 floats
    float (*res)[5] = (float (*)[5])(&tile[0][0] + 256);   // [138][5]
    int pw_id = gid - 6144;
    int oc = pw_id & 127;
    int b0 = (pw_id >> 7) * 4;
    zs[tid] = z[b0 * 64 + tid];
    __syncthreads();
    int row = tid;
    if (row < 138) {
      const float* wrow = (row == 0) ? gw + (size_t)oc * 64
                        : (row < 10) ? dww + ((size_t)oc * 9 + (row - 1)) * 64
                                     : pww + ((size_t)oc * 128 + (row - 10)) * 64;
      float wr[64];
      #pragma unroll
      for (int i = 0; i < 16; i++) {
        float4 v = ((const float4*)wrow)[i];
        wr[4*i] = v.x; wr[4*i+1] = v.y; wr[4*i+2] = v.z; wr[4*i+3] = v.w;
      }
      #pragma unroll
      for (int bb = 0; bb < 4; bb++) {
        float a = 0.f;
        #pragma unroll
        for (int i = 0; i < 64; i++) a += zs[bb * 64 + i] * wr[i];
        res[row][bb] = a;
      }
    }
    __syncthreads();
    for (int e = tid; e < 2304; e += 256) {   // bf162 units
      int icp = e & 15;
      int r1 = e >> 4;                  // 0..143
      int tap = r1 % 9, gb = r1 / 9;    // gb = bb*4+grp
      int grp = gb & 3, bb = gb >> 2;
      int b = b0 + bb;
      int ic = grp * 32 + icp * 2;
      int dy = tap / 3, dx = tap - dy * 3;
      float g = res[0][bb], d = res[1 + tap][bb];
      float p0 = res[10 + ic][bb], p1 = res[11 + ic][bb];
      const float* bp = base + ((size_t)(oc * 128 + ic)) * 9 + tap;
      __hip_bfloat162 o2 = {__float2bfloat16(bp[0] * g + p0 * d),
                            __float2bfloat16(bp[9] * g + p1 * d)};
      // dx-major slot (dx*3+dy) for conv's dx-outer phases
      *(__hip_bfloat162*)(Wt + ((((size_t)(b * 4 + grp)) * 9 + dx * 3 + dy) * 128 + oc) * 32 + icp * 2) = o2;
    }
  }
}

// ---------- conv: 256px x 64oc per block, 12 dx-outer phases, ONE barrier/steady phase ----------
// dbuf invariant: end-of-phase {vmcnt(0); barrier} certifies (a) this phase's reads done
// (overwrite target free next phase) and (b) this phase's stages block-visible.
// Boundary phases (fresh xt read same-phase) add a pre-compute {vmcnt(3); barrier}.
__global__ __launch_bounds__(256, 3) void conv_kernel(
    const __hip_bfloat16* __restrict__ xn, const __hip_bfloat16* __restrict__ Wt,
    float* __restrict__ out) {
  __shared__ __align__(16) char smem[49152];
  char* const xt  = smem;               // 24576 B (1536 slots; 1360 used)
  char* const wb0 = smem + 24576;       // 12288 B each
  char* const wb1 = smem + 36864;

  int bid = blockIdx.x;
  int X = bid & 7, q = bid >> 3;        // XCD grouping: 4 samples per XCD
  int logical = X * 288 + q;
  int b   = logical / 72;
  int rem = logical - b * 72;
  int ocg = rem & 1;
  int t36 = rem >> 1;
  int hr  = t36 / 3;
  int wc  = t36 - hr * 3;
  int h0 = hr * 8, w0 = wc * 32;

  int tid = threadIdx.x;
  int lane = tid & 63, wid = tid >> 6;
  int l15 = lane & 15, lk = lane >> 4;

  // x-stage source offsets (6/thread, clamp keeps per-wave issue count uniform)
  int xoff[6];
  #pragma unroll
  for (int j = 0; j < 6; j++) {
    int p = j * 256 + tid; if (p > 1359) p = 1359;
    int pair = p >> 3, v = (p & 7) ^ (pair & 7);
    int n = (pair << 1) | (v >> 2), k = v & 3;
    int hh = n / 34, ww = n - hh * 34;
    xoff[j] = ((h0 + hh) * 98 + (w0 + ww)) * 32 + k * 8;
  }
  // w-stage source offsets (3/thread), relative to the phase's 3-slot (dy) block
  int wsoff[3];
  #pragma unroll
  for (int i = 0; i < 3; i++) {
    int p = i * 256 + tid;
    int pair = p >> 3, v = (p & 7) ^ (pair & 7);
    int n = (pair << 1) | (v >> 2), k = v & 3;
    int dy = n >> 6, ocl = n & 63;
    wsoff[i] = (dy * 128 + ocg * 64 + ocl) * 32 + k * 8;
  }

  const __hip_bfloat16* xbase = xn + (size_t)b * 4 * 307328;
  const __hip_bfloat16* wbase = Wt + (size_t)b * 147456;

  f32x4 acc[4][4];
  #pragma unroll
  for (int i = 0; i < 4; i++)
    #pragma unroll
    for (int j = 0; j < 4; j++) acc[i][j] = (f32x4){0.f, 0.f, 0.f, 0.f};

  // prologue: w(phase0) -> wb0, then x(grp0) -> xt
  #pragma unroll
  for (int i = 0; i < 3; i++)
    load_lds16(wbase + wsoff[i], wb0 + ((i * 256 + wid * 64) << 4));
  #pragma unroll
  for (int j = 0; j < 6; j++)
    load_lds16(xbase + xoff[j], xt + ((j * 256 + wid * 64) << 4));

#define PHASE(S, G, DX, WCUR, WNXT, DOX, DOW, PRE)                                 \
  {                                                                                \
    if (DOX) {                                                                     \
      const __hip_bfloat16* xsrc = xbase + (size_t)(G) * 307328;                   \
      _Pragma("unroll")                                                            \
      for (int j = 0; j < 6; j++)                                                  \
        load_lds16(xsrc + xoff[j], xt + ((j * 256 + wid * 64) << 4));              \
    }                                                                              \
    if (DOW) {                                                                     \
      const __hip_bfloat16* wsrc = wbase + (size_t)((G) * 9 + (DX) * 3 + 3) * 4096;\
      _Pragma("unroll")                                                            \
      for (int i = 0; i < 3; i++)                                                  \
        load_lds16(wsrc + wsoff[i], (WNXT) + ((i * 256 + wid * 64) << 4));         \
    }                                                                              \
    if (PRE) {                                                                     \
      asm volatile("s_waitcnt vmcnt(3)" ::: "memory");                             \
      __builtin_amdgcn_s_barrier();                                                \
    }                                                                              \
    bf16x8 afr[4][2];                                                              \
    _Pragma("unroll")                                                              \
    for (int rr = 0; rr < 4; rr++)                                                 \
      _Pragma("unroll")                                                            \
      for (int cc = 0; cc < 2; cc++)                                               \
        afr[rr][cc] = *(const bf16x8*)(xt +                                        \
            swz((wid * 2 + rr) * 34 + cc * 16 + l15 + (DX), lk));                  \
    _Pragma("unroll")                                                              \
    for (int dy = 0; dy < 3; dy++) {                                               \
      bf16x8 bfr[4];                                                               \
      _Pragma("unroll")                                                            \
      for (int j = 0; j < 4; j++)                                                  \
        bfr[j] = *(const bf16x8*)((WCUR) + swz(dy * 64 + j * 16 + l15, lk));       \
      _Pragma("unroll")                                                            \
      for (int i = 0; i < 4; i++)                                                  \
        _Pragma("unroll")                                                          \
        for (int j = 0; j < 4; j++)                                                \
          acc[i][j] = __builtin_amdgcn_mfma_f32_16x16x32_bf16(                     \
              afr[(i >> 1) + dy][i & 1], bfr[j], acc[i][j], 0, 0, 0);              \
    }                                                                              \
    if ((S) < 11) {                                                                \
      asm volatile("s_waitcnt vmcnt(0)" ::: "memory");                             \
      __builtin_amdgcn_s_barrier();                                                \
    }                                                                              \
  }

  PHASE(0,  0, 0, wb0, wb1, 0, 1, 1)
  PHASE(1,  0, 1, wb1, wb0, 0, 1, 0)
  PHASE(2,  0, 2, wb0, wb1, 0, 1, 0)
  PHASE(3,  1, 0, wb1, wb0, 1, 1, 1)
  PHASE(4,  1, 1, wb0, wb1, 0, 1, 0)
  PHASE(5,  1, 2, wb1, wb0, 0, 1, 0)
  PHASE(6,  2, 0, wb0, wb1, 1, 1, 1)
  PHASE(7,  2, 1, wb1, wb0, 0, 1, 0)
  PHASE(8,  2, 2, wb0, wb1, 0, 1, 0)
  PHASE(9,  3, 0, wb1, wb0, 1, 1, 1)
  PHASE(10, 3, 1, wb0, wb1, 0, 1, 0)
  PHASE(11, 3, 2, wb1, wb0, 0, 0, 0)
#undef PHASE

  // epilogue: j-outer so each 128B output line completes in consecutive stores
  float* ob = out + ((size_t)b * 128 + ocg * 64) * 9216;
  #pragma unroll
  for (int j = 0; j < 4; j++) {
    int oc = j * 16 + l15;
    float* op = ob + (size_t)oc * 9216 + h0 * 96 + w0 + lk * 4;
    #pragma unroll
    for (int i = 0; i < 4; i++) {
      int m0 = wid * 64 + i * 16;
      *(f32x4*)(op + (m0 >> 5) * 96 + (m0 & 31)) = acc[i][j];
    }
  }
}

extern "C" void kernel_launch(void* const* d_in, const int* in_sizes, int n_in,
                              void* d_out, int out_size, void* d_ws, size_t ws_size,
                              hipStream_t stream) {
  const float* x   = (const float*)d_in[0];
  const float* z   = (const float*)d_in[1];
  const float* bw  = (const float*)d_in[2];
  const float* gw  = (const float*)d_in[3];
  const float* pww = (const float*)d_in[4];
  const float* dww = (const float*)d_in[5];
  float* out = (float*)d_out;

  char* ws = (char*)d_ws;
  __hip_bfloat16* xn = (__hip_bfloat16*)ws;                       // 78,675,968 B (padded)
  __hip_bfloat16* Wt = (__hip_bfloat16*)(ws + 78675968);          //  9,437,184 B

  hipLaunchKernelGGL(prep_kernel, dim3(7168), dim3(256), 0, stream,
                     x, z, gw, pww, dww, bw, xn, Wt);
  hipLaunchKernelGGL(conv_kernel, dim3(2304), dim3(256), 0, stream, xn, Wt, out);
}